// Round 7
// baseline (959.058 us; speedup 1.0000x reference)
//
#include <hip/hip_runtime.h>

#define NN 50000
#define DD 128
#define EE 800000
#define TT 400000
#define KM 32
#define UU 320  // uints per 640-col bf16 row
#define SCAN_TILE 2048
#define SCAN_NB ((NN + SCAN_TILE - 1) / SCAN_TILE)  // 25

static constexpr float INV_SQRT_D = 0.08838834764831845f; // 1/sqrt(128)
static constexpr float INV_D = 1.f / 128.f;

typedef __attribute__((ext_vector_type(8))) short bf16x8;
typedef __attribute__((ext_vector_type(4))) float f32x4;
typedef unsigned short ushort_t;

__device__ __forceinline__ float softplus_f(float x) {
  return (x > 20.f) ? x : log1pf(__expf(x));
}

__device__ __forceinline__ float gelu_tanh(float x) {
  float x3 = x * x * x;
  float u = 0.7978845608028654f * (x + 0.044715f * x3);
  u = fminf(fmaxf(u, -15.f), 15.f);
  float e = __expf(2.f * u);
  float t = (e - 1.f) / (e + 1.f);
  return 0.5f * x * (1.f + t);
}

__device__ __forceinline__ float wredsum(float v) {
#pragma unroll
  for (int m = 32; m; m >>= 1) v += __shfl_xor(v, m, 64);
  return v;
}

__device__ __forceinline__ float redsum16(float v) {
#pragma unroll
  for (int m = 1; m < 16; m <<= 1) v += __shfl_xor(v, m, 64);
  return v;
}

__device__ __forceinline__ float blo(unsigned w) { return __uint_as_float(w << 16); }
__device__ __forceinline__ float bhi(unsigned w) { return __uint_as_float(w & 0xffff0000u); }
__device__ __forceinline__ unsigned pack_bf16(float a, float b) {
  unsigned ua = __float_as_uint(a); ua += 0x7fff + ((ua >> 16) & 1);
  unsigned ub = __float_as_uint(b); ub += 0x7fff + ((ub >> 16) & 1);
  return (ua >> 16) | (ub & 0xffff0000u);
}
__device__ __forceinline__ ushort_t bf16_1(float x) {
  unsigned u = __float_as_uint(x); u += 0x7fff + ((u >> 16) & 1);
  return (ushort_t)(u >> 16);
}
__device__ __forceinline__ float bf16_back(float x) {
  unsigned u = __float_as_uint(x); u += 0x7fff + ((u >> 16) & 1);
  return __uint_as_float(u & 0xffff0000u);
}
__device__ __forceinline__ void unp8(uint4 w, float* f) {
  f[0] = blo(w.x); f[1] = bhi(w.x); f[2] = blo(w.y); f[3] = bhi(w.y);
  f[4] = blo(w.z); f[5] = bhi(w.z); f[6] = blo(w.w); f[7] = bhi(w.w);
}
__device__ __forceinline__ uint4 pk8(const float* f) {
  uint4 r;
  r.x = pack_bf16(f[0], f[1]); r.y = pack_bf16(f[2], f[3]);
  r.z = pack_bf16(f[4], f[5]); r.w = pack_bf16(f[6], f[7]);
  return r;
}

// params: [0]=b2 [1]=b3 [2]=bm [3]=cw2 [4]=cw3 [5]=cwm [6]=-sp2/b2 [7]=-sp3/b3 [8]=-spm/bm
__global__ void params_k(const float* l2, const float* l3, const float* lm,
                         const float* b2, const float* b3, const float* bm,
                         float* __restrict__ P) {
  if (threadIdx.x != 0) return;
  float B2 = fminf(softplus_f(b2[0]), 5.f);
  float B3 = fminf(softplus_f(b3[0]), 5.f);
  float Bm = fminf(softplus_f(bm[0]), 5.f);
  float S2 = softplus_f(l2[0]);
  float S3 = softplus_f(l3[0]);
  float Sm = softplus_f(lm[0]);
  P[0] = B2; P[1] = B3; P[2] = Bm;
  P[3] = -S2 * INV_SQRT_D; P[4] = -S3 * INV_D; P[5] = -Sm * INV_SQRT_D;
  P[6] = -S2 / B2; P[7] = -S3 / B3; P[8] = -Sm / Bm;
}

// ---------------- LayerNorm forward -> bf16 G ----------------
__global__ __launch_bounds__(256) void ln_fwd(const float* __restrict__ X,
                                              const float* __restrict__ gamma,
                                              const float* __restrict__ beta,
                                              unsigned* __restrict__ Gb,
                                              float* __restrict__ meanv,
                                              float* __restrict__ rstdv) {
  int row = blockIdx.x * 4 + (threadIdx.x >> 6);
  if (row >= NN) return;
  int l = threadIdx.x & 63;
  float2 x2 = *(const float2*)(X + row * DD + 2 * l);
  float mu = wredsum(x2.x + x2.y) * (1.f / DD);
  float d0 = x2.x - mu, d1 = x2.y - mu;
  float var = wredsum(d0 * d0 + d1 * d1) * (1.f / DD);
  float rstd = rsqrtf(var + 1e-5f);
  float2 g2 = *(const float2*)(gamma + 2 * l);
  float2 b2 = *(const float2*)(beta + 2 * l);
  float o0 = d0 * rstd * g2.x + b2.x;
  float o1 = d1 * rstd * g2.y + b2.y;
  Gb[(size_t)row * 64 + l] = pack_bf16(o0, o1);
  if (l == 0) { meanv[row] = mu; rstdv[row] = rstd; }
}

// ---------------- weight conversion ----------------
__global__ __launch_bounds__(256) void w_conv(const float* W0, const float* W1, const float* W2,
                                              const float* W3, const float* W4,
                                              ushort_t* __restrict__ Wt,
                                              ushort_t* __restrict__ Wc) {
  int idx = blockIdx.x * 256 + threadIdx.x;
  if (idx >= 640 * 128) return;
  const float* Ws[5] = {W0, W1, W2, W3, W4};
  int n = idx >> 7, k = idx & 127;
  Wt[idx] = bf16_1(Ws[n >> 7][(size_t)k * 128 + (n & 127)]);
  int k2 = idx >> 7, n2 = idx & 127;
  Wc[(size_t)n2 * 640 + k2] = bf16_1(Ws[k2 >> 7][(size_t)n2 * 128 + (k2 & 127)]);
}

// ---------------- fwd MFMA GEMM: QK[M,640](bf16) = Gb[M,128](bf16) @ Wt^T ----------------
__global__ __launch_bounds__(256) void mfma_fwd(const ushort_t* __restrict__ Gb,
                                                const ushort_t* __restrict__ Wt,
                                                ushort_t* __restrict__ QK, int M) {
  __shared__ ushort_t sB[64][136];
  int tid = threadIdx.x;
  int nb = blockIdx.y * 64;
  for (int idx = tid; idx < 64 * 16; idx += 256) {
    int r = idx >> 4, c8 = idx & 15;
    *(bf16x8*)&sB[r][c8 * 8] = *(const bf16x8*)(Wt + (size_t)(nb + r) * 128 + c8 * 8);
  }
  __syncthreads();
  int w = tid >> 6, l = tid & 63, quad = l >> 4, j = l & 15;
  int row0 = blockIdx.x * 64 + w * 16;
  int arow = row0 + j; if (arow >= M) arow = M - 1;
  const bf16x8* ap = (const bf16x8*)(Gb + (size_t)arow * 128);
  f32x4 acc[4];
#pragma unroll
  for (int nt = 0; nt < 4; nt++) acc[nt] = (f32x4){0.f, 0.f, 0.f, 0.f};
#pragma unroll
  for (int kc = 0; kc < 4; kc++) {
    bf16x8 a = ap[kc * 4 + quad];
#pragma unroll
    for (int nt = 0; nt < 4; nt++) {
      bf16x8 b = *(const bf16x8*)&sB[nt * 16 + j][kc * 32 + quad * 8];
      acc[nt] = __builtin_amdgcn_mfma_f32_16x16x32_bf16(a, b, acc[nt], 0, 0, 0);
    }
  }
#pragma unroll
  for (int nt = 0; nt < 4; nt++)
#pragma unroll
    for (int r = 0; r < 4; r++) {
      int row = row0 + quad * 4 + r;
      if (row < M) QK[(size_t)row * 640 + nb + nt * 16 + j] = bf16_1(acc[nt][r]);
    }
}

// ---------------- bwd MFMA GEMM: dG[M,128](bf16) = dAll[M,640](bf16) @ Wc^T ----------------
__global__ __launch_bounds__(256) void mfma_bwd(const ushort_t* __restrict__ dAll,
                                                const ushort_t* __restrict__ Wc,
                                                unsigned* __restrict__ dG, int M) {
  __shared__ ushort_t sB[64][40];
  int tid = threadIdx.x;
  int nb = blockIdx.y * 64;
  int w = tid >> 6, l = tid & 63, quad = l >> 4, j = l & 15;
  int row0 = blockIdx.x * 64 + w * 16;
  int arow = row0 + j; if (arow >= M) arow = M - 1;
  const ushort_t* arp = dAll + (size_t)arow * 640;
  f32x4 acc[4];
#pragma unroll
  for (int nt = 0; nt < 4; nt++) acc[nt] = (f32x4){0.f, 0.f, 0.f, 0.f};
  int sr = tid >> 2, sc = tid & 3;
  for (int kc = 0; kc < 20; kc++) {
    __syncthreads();
    *(bf16x8*)&sB[sr][sc * 8] = *(const bf16x8*)(Wc + (size_t)(nb + sr) * 640 + kc * 32 + sc * 8);
    __syncthreads();
    bf16x8 a = *(const bf16x8*)(arp + kc * 32 + quad * 8);
#pragma unroll
    for (int nt = 0; nt < 4; nt++) {
      bf16x8 b = *(const bf16x8*)&sB[nt * 16 + j][quad * 8];
      acc[nt] = __builtin_amdgcn_mfma_f32_16x16x32_bf16(a, b, acc[nt], 0, 0, 0);
    }
  }
#pragma unroll
  for (int nt = 0; nt < 4; nt++)
#pragma unroll
    for (int r = 0; r < 4; r++) {
      int row = row0 + quad * 4 + r;
      if (row < M) ((ushort_t*)dG)[(size_t)row * 128 + nb + nt * 16 + j] = bf16_1(acc[nt][r]);
    }
}

// ---------------- small fp32 GEMM for Km = B_mem @ W_Km ----------------
__global__ __launch_bounds__(256, 1) void gemm_km(const float* __restrict__ A,
                                                  const float* __restrict__ W,
                                                  float* __restrict__ C, int M) {
  __shared__ float As[32][132];
  __shared__ float Wst[128][136];
  const int tid = threadIdx.x;
  for (int idx = tid; idx < 128 * 128; idx += 256) {
    int k = idx >> 7, jj = idx & 127;
    Wst[k][jj] = W[k * 128 + jj];
  }
  for (int idx = tid; idx < 32 * 128; idx += 256) {
    int r = idx >> 7, d = idx & 127;
    As[r][d] = A[r * 128 + d];
  }
  __syncthreads();
  int r = tid >> 3, c0 = (tid & 7) * 16;
  float acc[16];
#pragma unroll
  for (int q = 0; q < 16; q++) acc[q] = 0.f;
  for (int k = 0; k < 128; k++) {
    float av = As[r][k];
#pragma unroll
    for (int q = 0; q < 16; q++) acc[q] = fmaf(av, Wst[k][c0 + q], acc[q]);
  }
#pragma unroll
  for (int q = 0; q < 16; q++) C[r * 128 + c0 + q] = acc[q];
}

// ---------------- edge MLP via split-bf16 double MFMA: one wave = 16 edges ----------------
// EA = hi+lo, W = Whi+Wlo. MFMA1: A=[hi|lo], B=[Whi|Whi] -> (hi+lo)Whi.
// MFMA2: A=[hi|0], B=[Wlo|0] -> hi*Wlo. Residual err ~ lo*Wlo ~ 2^-16.
__global__ __launch_bounds__(256) void edge_mlp(const float* __restrict__ EA,
                                                const float* __restrict__ We1,
                                                const float* __restrict__ be1,
                                                const float* __restrict__ We2,
                                                const float* __restrict__ be2,
                                                float* __restrict__ a2) {
  __shared__ float sW1[16 * 128];
  __shared__ float sb1[128];
  __shared__ float sW2[128];
  int tid = threadIdx.x;
  for (int i = tid; i < 2048; i += 256) sW1[i] = We1[i];
  if (tid < 128) { sb1[tid] = be1[tid]; sW2[tid] = We2[tid]; }
  __syncthreads();
  int w = tid >> 6, l = tid & 63;
  int m = l & 15, q = l >> 4;
  union u8 { bf16x8 v; ushort_t s[8]; };
  u8 bfh[8], bfl[8];
  float bb[8], ww[8];
#pragma unroll
  for (int nt = 0; nt < 8; nt++) {
    int n = nt * 16 + m;
#pragma unroll
    for (int j = 0; j < 8; j++) {
      int k = q * 8 + j;
      int kk = k & 15;
      float wv = sW1[kk * 128 + n];
      bfh[nt].s[j] = bf16_1(wv);
      bfl[nt].s[j] = (k < 16) ? bf16_1(wv - bf16_back(wv)) : (ushort_t)0;
    }
    bb[nt] = sb1[n];
    ww[nt] = sW2[n];
  }
  float be2v = be2[0];
  for (int batch = 0; batch < 4; batch++) {
    int e0 = blockIdx.x * 256 + batch * 64 + w * 16;
    u8 af, a2f;
    {
      int qq = q & 1;
      const float* ep = EA + (size_t)(e0 + m) * 16 + qq * 8;
      float4 v0 = *(const float4*)ep;
      float4 v1 = *(const float4*)(ep + 4);
      float xs[8] = {v0.x, v0.y, v0.z, v0.w, v1.x, v1.y, v1.z, v1.w};
      if (q < 2) {
#pragma unroll
        for (int j = 0; j < 8; j++) { af.s[j] = bf16_1(xs[j]); a2f.s[j] = af.s[j]; }
      } else {
#pragma unroll
        for (int j = 0; j < 8; j++) { af.s[j] = bf16_1(xs[j] - bf16_back(xs[j])); a2f.s[j] = 0; }
      }
    }
    f32x4 z4 = (f32x4){0.f, 0.f, 0.f, 0.f};
    float s0 = 0.f, s1 = 0.f, s2 = 0.f, s3 = 0.f;
#pragma unroll
    for (int nt = 0; nt < 8; nt++) {
      f32x4 acc = __builtin_amdgcn_mfma_f32_16x16x32_bf16(af.v, bfh[nt].v, z4, 0, 0, 0);
      acc = __builtin_amdgcn_mfma_f32_16x16x32_bf16(a2f.v, bfl[nt].v, acc, 0, 0, 0);
      float bias = bb[nt], w2v = ww[nt];
      s0 = fmaf(gelu_tanh(acc[0] + bias), w2v, s0);
      s1 = fmaf(gelu_tanh(acc[1] + bias), w2v, s1);
      s2 = fmaf(gelu_tanh(acc[2] + bias), w2v, s2);
      s3 = fmaf(gelu_tanh(acc[3] + bias), w2v, s3);
    }
    s0 = redsum16(s0); s1 = redsum16(s1); s2 = redsum16(s2); s3 = redsum16(s3);
    if (m == 0) {
      int eb = e0 + q * 4;
      a2[eb + 0] = s0 + be2v;
      a2[eb + 1] = s1 + be2v;
      a2[eb + 2] = s2 + be2v;
      a2[eb + 3] = s3 + be2v;
    }
  }
}

// ---------------- CSR build ----------------
__global__ __launch_bounds__(256) void hist2(const int* __restrict__ a,
                                             const int* __restrict__ b,
                                             int* __restrict__ ca,
                                             int* __restrict__ cb, int n) {
  int e = blockIdx.x * 256 + threadIdx.x;
  if (e >= n) return;
  atomicAdd(&ca[a[e]], 1);
  atomicAdd(&cb[b[e]], 1);
}

__global__ __launch_bounds__(256) void hist_t3(const int* __restrict__ c,
                                               const int* __restrict__ u,
                                               const int* __restrict__ v,
                                               int* __restrict__ cc,
                                               int* __restrict__ cuv, int n) {
  int t = blockIdx.x * 256 + threadIdx.x;
  if (t >= n) return;
  atomicAdd(&cc[c[t]], 1);
  atomicAdd(&cuv[u[t]], 1);
  atomicAdd(&cuv[v[t]], 1);
}

// ---------------- parallel 3-phase scan over 4 count arrays ----------------
__global__ __launch_bounds__(256) void scan_p1(const int* __restrict__ cnt,
                                               int* __restrict__ part) {
  int arr = blockIdx.y, b = blockIdx.x;
  const int* c = cnt + (size_t)arr * NN;
  int gi = b * SCAN_TILE + threadIdx.x * 8;
  int s = 0;
#pragma unroll
  for (int t = 0; t < 8; t++) s += (gi + t < NN) ? c[gi + t] : 0;
#pragma unroll
  for (int m = 32; m; m >>= 1) s += __shfl_xor(s, m, 64);
  __shared__ int wt[4];
  int lane = threadIdx.x & 63, wid = threadIdx.x >> 6;
  if (lane == 0) wt[wid] = s;
  __syncthreads();
  if (threadIdx.x == 0) part[arr * SCAN_NB + b] = wt[0] + wt[1] + wt[2] + wt[3];
}

__global__ __launch_bounds__(256) void scan_p2(int* __restrict__ part) {
  int w = threadIdx.x >> 6, l = threadIdx.x & 63;
  int v = (l < SCAN_NB) ? part[w * SCAN_NB + l] : 0;
  int x = v;
#pragma unroll
  for (int d = 1; d < 64; d <<= 1) {
    int y = __shfl_up(x, d, 64);
    if (l >= d) x += y;
  }
  if (l < SCAN_NB) part[w * SCAN_NB + l] = x - v;
}

__global__ __launch_bounds__(256) void scan_p3(const int* __restrict__ cnt,
                                               const int* __restrict__ part,
                                               int* __restrict__ rowptr,
                                               int* __restrict__ cursor) {
  int arr = blockIdx.y, b = blockIdx.x;
  const int* c = cnt + (size_t)arr * NN;
  int* rp = rowptr + (size_t)arr * (NN + 1);
  int* cur = cursor + (size_t)arr * NN;
  int tid = threadIdx.x;
  int gi = b * SCAN_TILE + tid * 8;
  int vals[8];
#pragma unroll
  for (int t = 0; t < 8; t++) vals[t] = (gi + t < NN) ? c[gi + t] : 0;
  int tsum = 0;
#pragma unroll
  for (int t = 0; t < 8; t++) tsum += vals[t];
  int lane = tid & 63, wid = tid >> 6;
  int x = tsum;
#pragma unroll
  for (int d = 1; d < 64; d <<= 1) {
    int y = __shfl_up(x, d, 64);
    if (lane >= d) x += y;
  }
  __shared__ int wt[4];
  if (lane == 63) wt[wid] = x;
  __syncthreads();
  int wadd = 0;
  for (int w = 0; w < wid; w++) wadd += wt[w];
  int running = part[arr * SCAN_NB + b] + wadd + x - tsum;
#pragma unroll
  for (int t = 0; t < 8; t++) {
    if (gi + t < NN) { rp[gi + t] = running; cur[gi + t] = running; }
    running += vals[t];
  }
  if (b == SCAN_NB - 1 && tid == 255) rp[NN] = running;
}

// ---------------- scatter with packed 8B payloads ----------------
// c2-CSR entry: (u, a2 bits); u2-CSR entry: (slot, c)
__global__ __launch_bounds__(256) void scat2(const int* __restrict__ c2,
                                             const int* __restrict__ u2,
                                             const float* __restrict__ a2,
                                             int* __restrict__ cuc,
                                             int* __restrict__ cuu,
                                             int2* __restrict__ ec2,
                                             int2* __restrict__ eu2, int n) {
  int e = blockIdx.x * 256 + threadIdx.x;
  if (e >= n) return;
  int c = c2[e], u = u2[e];
  int p = atomicAdd(&cuc[c], 1);
  int2 w0; w0.x = u; w0.y = __float_as_int(a2[e]);
  ec2[p] = w0;
  int p2 = atomicAdd(&cuu[u], 1);
  int2 w1; w1.x = p; w1.y = c;
  eu2[p2] = w1;
}

// c3-CSR entry: (u | v<<16, ta); uv-CSR entry: (o | c<<16, slot<<1|ta)
__global__ __launch_bounds__(256) void scat_t3(const int* __restrict__ c3,
                                               const int* __restrict__ u3,
                                               const int* __restrict__ v3,
                                               const int* __restrict__ ttau,
                                               int* __restrict__ cuc,
                                               int* __restrict__ cuv,
                                               int2* __restrict__ tc3,
                                               int2* __restrict__ tuv, int n) {
  int t = blockIdx.x * 256 + threadIdx.x;
  if (t >= n) return;
  int c = c3[t], u = u3[t], v = v3[t], ta = ttau[t] & 1;
  int p = atomicAdd(&cuc[c], 1);
  int2 w0; w0.x = u | (v << 16); w0.y = ta;
  tc3[p] = w0;
  int sp = (p << 1) | ta;
  int q1 = atomicAdd(&cuv[u], 1);
  int2 w1; w1.x = v | (c << 16); w1.y = sp;
  tuv[q1] = w1;
  int q2 = atomicAdd(&cuv[v], 1);
  int2 w2; w2.x = u | (c << 16); w2.y = sp;
  tuv[q2] = w2;
}

// ---------------- fused e2 fwd + dQ2 (3-deep pipeline) ----------------
__global__ __launch_bounds__(256) void e2_fused(const unsigned* __restrict__ QK,
                                                const float* __restrict__ P,
                                                const int2* __restrict__ ec2,
                                                const int* __restrict__ rp,
                                                float* __restrict__ s2c,
                                                float* __restrict__ L2,
                                                unsigned* __restrict__ dAll) {
  int row = blockIdx.x * 4 + (threadIdx.x >> 6);
  if (row >= NN) return;
  int l = threadIdx.x & 63, g = l >> 4, j = l & 15;
  float b2s = P[0] * INV_SQRT_D, cw2 = P[3];
  float q[8];
  unp8(*(const uint4*)(QK + (size_t)row * UU + j * 4), q);
  int s = rp[row], e = rp[row + 1];
  float m = -3.0e38f, z = 0.f;
  float acc[8] = {0.f, 0.f, 0.f, 0.f, 0.f, 0.f, 0.f, 0.f};
  int i0 = s + g;
  uint4 kA = {0, 0, 0, 0}, kB = {0, 0, 0, 0};
  float aA = 0.f, aB = 0.f;
  if (i0 < e) {
    int2 ce = ec2[i0]; aA = __int_as_float(ce.y);
    kA = *(const uint4*)(QK + (size_t)ce.x * UU + 64 + j * 4);
  }
  if (i0 + 4 < e) {
    int2 ce = ec2[i0 + 4]; aB = __int_as_float(ce.y);
    kB = *(const uint4*)(QK + (size_t)ce.x * UU + 64 + j * 4);
  }
  for (int i = i0; i < e; i += 4) {
    uint4 kC = {0, 0, 0, 0}; float aC = 0.f;
    if (i + 8 < e) {
      int2 ce = ec2[i + 8]; aC = __int_as_float(ce.y);
      kC = *(const uint4*)(QK + (size_t)ce.x * UU + 64 + j * 4);
    }
    float k[8]; unp8(kA, k);
    float d = 0.f;
#pragma unroll
    for (int t = 0; t < 8; t++) d = fmaf(q[t], k[t], d);
    d = redsum16(d);
    float sv = b2s * d + aA;
    if (j == 0) s2c[i] = sv;
    if (sv <= m) {
      float p = __expf(sv - m);
      z += p;
#pragma unroll
      for (int t = 0; t < 8; t++) acc[t] = fmaf(p, k[t], acc[t]);
    } else {
      float r = __expf(m - sv);
      z = fmaf(z, r, 1.f);
#pragma unroll
      for (int t = 0; t < 8; t++) acc[t] = fmaf(acc[t], r, k[t]);
      m = sv;
    }
    kA = kB; aA = aB; kB = kC; aB = aC;
  }
  float mx = fmaxf(m, __shfl_xor(m, 16, 64));
  mx = fmaxf(mx, __shfl_xor(mx, 32, 64));
  float r = (z > 0.f) ? __expf(m - mx) : 0.f;
  float zz = z * r;
  zz += __shfl_xor(zz, 16, 64);
  zz += __shfl_xor(zz, 32, 64);
#pragma unroll
  for (int t = 0; t < 8; t++) {
    float v = acc[t] * r;
    v += __shfl_xor(v, 16, 64);
    v += __shfl_xor(v, 32, 64);
    acc[t] = v;
  }
  if (l == 0) L2[row] = (zz > 0.f) ? (mx + __logf(zz)) : 0.f;
  if (g == 0) {
    float coef = (zz > 0.f) ? cw2 / zz : 0.f;
    float o[8];
#pragma unroll
    for (int t = 0; t < 8; t++) o[t] = coef * acc[t];
    *(uint4*)(dAll + (size_t)row * UU + 0 + j * 4) = pk8(o);
  }
}

// ---------------- dK2 gather (3-deep pipeline) ----------------
__global__ __launch_bounds__(256) void dk2_gather(const unsigned* __restrict__ QK,
                                                  const float* __restrict__ s2c,
                                                  const float* __restrict__ L2,
                                                  const float* __restrict__ P,
                                                  const int2* __restrict__ eu2,
                                                  const int* __restrict__ rp,
                                                  unsigned* __restrict__ dAll) {
  int row = blockIdx.x * 4 + (threadIdx.x >> 6);
  if (row >= NN) return;
  int l = threadIdx.x & 63, g = l >> 4, j = l & 15;
  float cw2 = P[3];
  int s = rp[row], e = rp[row + 1];
  float acc[8] = {0.f, 0.f, 0.f, 0.f, 0.f, 0.f, 0.f, 0.f};
  int i0 = s + g;
  uint4 qA = {0, 0, 0, 0}, qB = {0, 0, 0, 0};
  float scA = 0.f, lcA = 0.f, scB = 0.f, lcB = 0.f;
  if (i0 < e) {
    int2 ue = eu2[i0]; scA = s2c[ue.x]; lcA = L2[ue.y];
    qA = *(const uint4*)(QK + (size_t)ue.y * UU + 0 + j * 4);
  }
  if (i0 + 4 < e) {
    int2 ue = eu2[i0 + 4]; scB = s2c[ue.x]; lcB = L2[ue.y];
    qB = *(const uint4*)(QK + (size_t)ue.y * UU + 0 + j * 4);
  }
  for (int i = i0; i < e; i += 4) {
    uint4 qC = {0, 0, 0, 0}; float scC = 0.f, lcC = 0.f;
    if (i + 8 < e) {
      int2 ue = eu2[i + 8]; scC = s2c[ue.x]; lcC = L2[ue.y];
      qC = *(const uint4*)(QK + (size_t)ue.y * UU + 0 + j * 4);
    }
    float w = cw2 * __expf(scA - lcA);
    float qv[8]; unp8(qA, qv);
#pragma unroll
    for (int t = 0; t < 8; t++) acc[t] = fmaf(w, qv[t], acc[t]);
    qA = qB; scA = scB; lcA = lcB;
    qB = qC; scB = scC; lcB = lcC;
  }
#pragma unroll
  for (int t = 0; t < 8; t++) {
    float v = acc[t];
    v += __shfl_xor(v, 16, 64);
    v += __shfl_xor(v, 32, 64);
    acc[t] = v;
  }
  if (g == 0) *(uint4*)(dAll + (size_t)row * UU + 64 + j * 4) = pk8(acc);
}

// ---------------- fused t3 fwd + dQ3 (3-deep pipeline) ----------------
__global__ __launch_bounds__(256) void t3_fused(const unsigned* __restrict__ QK,
                                                const float* __restrict__ Tt,
                                                const float* __restrict__ P,
                                                const int2* __restrict__ tc3,
                                                const int* __restrict__ rp,
                                                float* __restrict__ s3c,
                                                float* __restrict__ L3,
                                                unsigned* __restrict__ dAll) {
  __shared__ float sT[2 * DD];
  int tid = threadIdx.x;
  sT[tid] = Tt[tid];
  __syncthreads();
  int row = blockIdx.x * 4 + (tid >> 6);
  if (row >= NN) return;
  int l = tid & 63, g = l >> 4, j = l & 15;
  float b3s = P[1] * INV_D, cw3 = P[4];
  float q[8];
  unp8(*(const uint4*)(QK + (size_t)row * UU + 128 + j * 4), q);
  int s = rp[row], e = rp[row + 1];
  float m = -3.0e38f, z = 0.f;
  float acc[8] = {0.f, 0.f, 0.f, 0.f, 0.f, 0.f, 0.f, 0.f};
  int i0 = s + g;
  uint4 kuA = {0, 0, 0, 0}, kvA = {0, 0, 0, 0};
  uint4 kuB = {0, 0, 0, 0}, kvB = {0, 0, 0, 0};
  int taA = 0, taB = 0;
  if (i0 < e) {
    int2 te = tc3[i0]; taA = te.y;
    int u = te.x & 0xffff, v = ((unsigned)te.x) >> 16;
    kuA = *(const uint4*)(QK + (size_t)u * UU + 192 + j * 4);
    kvA = *(const uint4*)(QK + (size_t)v * UU + 192 + j * 4);
  }
  if (i0 + 4 < e) {
    int2 te = tc3[i0 + 4]; taB = te.y;
    int u = te.x & 0xffff, v = ((unsigned)te.x) >> 16;
    kuB = *(const uint4*)(QK + (size_t)u * UU + 192 + j * 4);
    kvB = *(const uint4*)(QK + (size_t)v * UU + 192 + j * 4);
  }
  for (int i = i0; i < e; i += 4) {
    uint4 kuC = {0, 0, 0, 0}, kvC = {0, 0, 0, 0}; int taC = 0;
    if (i + 8 < e) {
      int2 te = tc3[i + 8]; taC = te.y;
      int u = te.x & 0xffff, v = ((unsigned)te.x) >> 16;
      kuC = *(const uint4*)(QK + (size_t)u * UU + 192 + j * 4);
      kvC = *(const uint4*)(QK + (size_t)v * UU + 192 + j * 4);
    }
    float ku[8], kv[8]; unp8(kuA, ku); unp8(kvA, kv);
    const float* tv = &sT[taA * DD + j * 8];
    float et[8], d = 0.f;
#pragma unroll
    for (int t = 0; t < 8; t++) { et[t] = ku[t] * kv[t] * tv[t]; d = fmaf(q[t], et[t], d); }
    d = redsum16(d);
    float sv = b3s * d;
    if (j == 0) s3c[i] = sv;
    if (sv <= m) {
      float p = __expf(sv - m);
      z += p;
#pragma unroll
      for (int t = 0; t < 8; t++) acc[t] = fmaf(p, et[t], acc[t]);
    } else {
      float r = __expf(m - sv);
      z = fmaf(z, r, 1.f);
#pragma unroll
      for (int t = 0; t < 8; t++) acc[t] = fmaf(acc[t], r, et[t]);
      m = sv;
    }
    kuA = kuB; kvA = kvB; taA = taB;
    kuB = kuC; kvB = kvC; taB = taC;
  }
  float mx = fmaxf(m, __shfl_xor(m, 16, 64));
  mx = fmaxf(mx, __shfl_xor(mx, 32, 64));
  float r = (z > 0.f) ? __expf(m - mx) : 0.f;
  float zz = z * r;
  zz += __shfl_xor(zz, 16, 64);
  zz += __shfl_xor(zz, 32, 64);
#pragma unroll
  for (int t = 0; t < 8; t++) {
    float v = acc[t] * r;
    v += __shfl_xor(v, 16, 64);
    v += __shfl_xor(v, 32, 64);
    acc[t] = v;
  }
  if (l == 0) L3[row] = (zz > 0.f) ? (mx + __logf(zz)) : 0.f;
  if (g == 0) {
    float coef = (zz > 0.f) ? cw3 / zz : 0.f;
    float o[8];
#pragma unroll
    for (int t = 0; t < 8; t++) o[t] = coef * acc[t];
    *(uint4*)(dAll + (size_t)row * UU + 128 + j * 4) = pk8(o);
  }
}

// ---------------- dK3 gather (3-deep pipeline) ----------------
__global__ __launch_bounds__(256) void dk3_gather(const unsigned* __restrict__ QK,
                                                  const float* __restrict__ Tt,
                                                  const float* __restrict__ s3c,
                                                  const float* __restrict__ L3,
                                                  const float* __restrict__ P,
                                                  const int2* __restrict__ tuv,
                                                  const int* __restrict__ rp,
                                                  unsigned* __restrict__ dAll) {
  __shared__ float sT[2 * DD];
  int tid = threadIdx.x;
  sT[tid] = Tt[tid];
  __syncthreads();
  int row = blockIdx.x * 4 + (tid >> 6);
  if (row >= NN) return;
  int l = tid & 63, g = l >> 4, j = l & 15;
  float cw3 = P[4];
  int s = rp[row], e = rp[row + 1];
  float acc[8] = {0.f, 0.f, 0.f, 0.f, 0.f, 0.f, 0.f, 0.f};
  int i0 = s + g;
  uint4 qA = {0, 0, 0, 0}, kA = {0, 0, 0, 0};
  uint4 qB = {0, 0, 0, 0}, kB = {0, 0, 0, 0};
  int taA = 0, taB = 0;
  float scA = 0.f, lcA = 0.f, scB = 0.f, lcB = 0.f;
  if (i0 < e) {
    int2 ue = tuv[i0];
    int o = ue.x & 0xffff, c = ((unsigned)ue.x) >> 16;
    taA = ue.y & 1; scA = s3c[ue.y >> 1]; lcA = L3[c];
    qA = *(const uint4*)(QK + (size_t)c * UU + 128 + j * 4);
    kA = *(const uint4*)(QK + (size_t)o * UU + 192 + j * 4);
  }
  if (i0 + 4 < e) {
    int2 ue = tuv[i0 + 4];
    int o = ue.x & 0xffff, c = ((unsigned)ue.x) >> 16;
    taB = ue.y & 1; scB = s3c[ue.y >> 1]; lcB = L3[c];
    qB = *(const uint4*)(QK + (size_t)c * UU + 128 + j * 4);
    kB = *(const uint4*)(QK + (size_t)o * UU + 192 + j * 4);
  }
  for (int i = i0; i < e; i += 4) {
    uint4 qC = {0, 0, 0, 0}, kC = {0, 0, 0, 0}; int taC = 0;
    float scC = 0.f, lcC = 0.f;
    if (i + 8 < e) {
      int2 ue = tuv[i + 8];
      int o = ue.x & 0xffff, c = ((unsigned)ue.x) >> 16;
      taC = ue.y & 1; scC = s3c[ue.y >> 1]; lcC = L3[c];
      qC = *(const uint4*)(QK + (size_t)c * UU + 128 + j * 4);
      kC = *(const uint4*)(QK + (size_t)o * UU + 192 + j * 4);
    }
    float w = cw3 * __expf(scA - lcA);
    float qv[8], ko[8]; unp8(qA, qv); unp8(kA, ko);
    const float* tv = &sT[taA * DD + j * 8];
#pragma unroll
    for (int t = 0; t < 8; t++) acc[t] = fmaf(w * tv[t], qv[t] * ko[t], acc[t]);
    qA = qB; kA = kB; taA = taB; scA = scB; lcA = lcB;
    qB = qC; kB = kC; taB = taC; scB = scC; lcB = lcC;
  }
#pragma unroll
  for (int t = 0; t < 8; t++) {
    float v = acc[t];
    v += __shfl_xor(v, 16, 64);
    v += __shfl_xor(v, 32, 64);
    acc[t] = v;
  }
  if (g == 0) *(uint4*)(dAll + (size_t)row * UU + 192 + j * 4) = pk8(acc);
}

// ---------------- memory-bank energy ----------------
__global__ __launch_bounds__(256) void em_row(const unsigned* __restrict__ QK,
                                              const float* __restrict__ Km,
                                              const float* __restrict__ P,
                                              unsigned* __restrict__ dAll,
                                              float* __restrict__ Lm) {
  __shared__ float sKm[KM * DD];
  int tid = threadIdx.x;
  for (int i = tid; i < KM * DD; i += 256) sKm[i] = Km[i];
  __syncthreads();
  int row = blockIdx.x * 4 + (tid >> 6);
  if (row >= NN) return;
  int l = tid & 63, g = l >> 4, j = l & 15;
  float bms = P[2] * INV_SQRT_D, cwm = P[5];
  float q[8];
  unp8(*(const uint4*)(QK + (size_t)row * UU + 256 + j * 4), q);
  float dk[8];
#pragma unroll
  for (int kk = 0; kk < 8; kk++) {
    int k = g * 8 + kk;
    const float* kr = &sKm[k * DD + j * 8];
    float d = 0.f;
#pragma unroll
    for (int t = 0; t < 8; t++) d = fmaf(q[t], kr[t], d);
    dk[kk] = redsum16(d) * bms;
  }
  float m = dk[0];
#pragma unroll
  for (int kk = 1; kk < 8; kk++) m = fmaxf(m, dk[kk]);
  float mx = fmaxf(m, __shfl_xor(m, 16, 64));
  mx = fmaxf(mx, __shfl_xor(mx, 32, 64));
  float p[8], z = 0.f;
#pragma unroll
  for (int kk = 0; kk < 8; kk++) { p[kk] = __expf(dk[kk] - mx); z += p[kk]; }
  float zz = z;
  zz += __shfl_xor(zz, 16, 64);
  zz += __shfl_xor(zz, 32, 64);
  if (l == 0) Lm[row] = mx + __logf(zz);
  float coef = cwm / zz;
  float acc[8] = {0.f, 0.f, 0.f, 0.f, 0.f, 0.f, 0.f, 0.f};
#pragma unroll
  for (int kk = 0; kk < 8; kk++) {
    int k = g * 8 + kk;
    const float* kr = &sKm[k * DD + j * 8];
    float pc_ = p[kk] * coef;
#pragma unroll
    for (int t = 0; t < 8; t++) acc[t] = fmaf(pc_, kr[t], acc[t]);
  }
#pragma unroll
  for (int t = 0; t < 8; t++) {
    float v = acc[t];
    v += __shfl_xor(v, 16, 64);
    v += __shfl_xor(v, 32, 64);
    acc[t] = v;
  }
  if (g == 0) *(uint4*)(dAll + (size_t)row * UU + 256 + j * 4) = pk8(acc);
}

// ---------------- LN backward + clips + update ----------------
__global__ __launch_bounds__(256) void ln_bwd(const float* __restrict__ X,
                                              const unsigned* __restrict__ dG,
                                              const float* __restrict__ gamma,
                                              const float* __restrict__ meanv,
                                              const float* __restrict__ rstdv,
                                              float* __restrict__ out) {
  int row = blockIdx.x * 4 + (threadIdx.x >> 6);
  if (row >= NN) return;
  int l = threadIdx.x & 63;
  float mu = meanv[row], rstd = rstdv[row];
  float2 x2 = *(const float2*)(X + row * DD + 2 * l);
  unsigned gw = dG[(size_t)row * 64 + l];
  float2 ga = *(const float2*)(gamma + 2 * l);
  float xh0 = (x2.x - mu) * rstd, xh1 = (x2.y - mu) * rstd;
  float dh0 = blo(gw) * ga.x, dh1 = bhi(gw) * ga.y;
  float sa = wredsum(dh0 + dh1) * (1.f / DD);
  float sb = wredsum(dh0 * xh0 + dh1 * xh1) * (1.f / DD);
  float dx0 = rstd * (dh0 - sa - xh0 * sb);
  float dx1 = rstd * (dh1 - sa - xh1 * sb);
  float gn = fmaxf(sqrtf(wredsum(dx0 * dx0 + dx1 * dx1)), 1e-6f);
  float sc = fminf(1.f / gn, 1.f);
  dx0 *= sc; dx1 *= sc;
  float xn0 = x2.x - 0.1f * 0.9999f * dx0;
  float xn1 = x2.y - 0.1f * 0.9999f * dx1;
  float sn = fmaxf(sqrtf(wredsum(xn0 * xn0 + xn1 * xn1)), 1e-6f);
  float sc2 = fminf(10.f / sn, 1.f);
  float2 o; o.x = xn0 * sc2; o.y = xn1 * sc2;
  *(float2*)(out + row * DD + 2 * l) = o;
}

// ---------------- final energy scalar (parallel, atomic) ----------------
__global__ __launch_bounds__(256) void eval_write(const float* __restrict__ L2,
                                                  const float* __restrict__ L3,
                                                  const float* __restrict__ Lm,
                                                  const float* __restrict__ P,
                                                  float* __restrict__ out) {
  int i = blockIdx.x * 256 + threadIdx.x;
  float a2 = 0.f, a3 = 0.f, am = 0.f;
  if (i < NN) { a2 = L2[i]; a3 = L3[i]; am = Lm[i]; }
  a2 = wredsum(a2); a3 = wredsum(a3); am = wredsum(am);
  __shared__ float r2[4], r3[4], rm[4];
  int wv = threadIdx.x >> 6, l = threadIdx.x & 63;
  if (l == 0) { r2[wv] = a2; r3[wv] = a3; rm[wv] = am; }
  __syncthreads();
  if (threadIdx.x == 0) {
    float S2 = r2[0] + r2[1] + r2[2] + r2[3];
    float S3 = r3[0] + r3[1] + r3[2] + r3[3];
    float Sm = rm[0] + rm[1] + rm[2] + rm[3];
    atomicAdd(out, P[6] * S2 + P[7] * S3 + P[8] * Sm);
  }
}

extern "C" void kernel_launch(void* const* d_in, const int* in_sizes, int n_in,
                              void* d_out, int out_size, void* d_ws, size_t ws_size,
                              hipStream_t stream) {
  (void)in_sizes; (void)n_in; (void)out_size;
  const float* X = (const float*)d_in[0];
  const float* EA = (const float*)d_in[1];
  const float* ln_g = (const float*)d_in[2];
  const float* ln_b = (const float*)d_in[3];
  const float* W_Q2 = (const float*)d_in[4];
  const float* W_K2 = (const float*)d_in[5];
  const float* W_Q3 = (const float*)d_in[6];
  const float* W_K3 = (const float*)d_in[7];
  const float* T_tau = (const float*)d_in[8];
  const float* W_Qm = (const float*)d_in[9];
  const float* W_Km = (const float*)d_in[10];
  const float* B_mem = (const float*)d_in[11];
  const float* We1 = (const float*)d_in[12];
  const float* be1 = (const float*)d_in[13];
  const float* We2 = (const float*)d_in[14];
  const float* be2 = (const float*)d_in[15];
  const float* l2s = (const float*)d_in[16];
  const float* l3s = (const float*)d_in[17];
  const float* lms = (const float*)d_in[18];
  const float* b2s = (const float*)d_in[19];
  const float* b3s = (const float*)d_in[20];
  const float* bms = (const float*)d_in[21];
  const int* c2 = (const int*)d_in[22];
  const int* u2 = (const int*)d_in[23];
  const int* c3 = (const int*)d_in[24];
  const int* u3 = (const int*)d_in[25];
  const int* v3 = (const int*)d_in[26];
  const int* ttau = (const int*)d_in[27];
  float* out = (float*)d_out;

  float* ws = (float*)d_ws;
  size_t off = 0;
  auto alloc = [&](size_t n) { float* p = ws + off; off += n; return p; };
  const size_t ND = (size_t)NN * DD;
  unsigned* Gb = (unsigned*)alloc(ND / 2);
  unsigned* QKall = (unsigned*)alloc((size_t)NN * UU);
  unsigned* dAll = (unsigned*)alloc((size_t)NN * UU);
  unsigned* dG = (unsigned*)alloc(ND / 2);
  ushort_t* Wt5 = (ushort_t*)alloc(640 * 128 / 2);
  ushort_t* Wcat = (ushort_t*)alloc(640 * 128 / 2);
  float* Km = alloc((size_t)KM * DD);
  float* a2 = alloc(EE);
  float* s2c = alloc(EE);
  float* s3c = alloc(TT);
  float* meanv = alloc(NN);
  float* rstdv = alloc(NN);
  float* L2 = alloc(NN);
  float* L3 = alloc(NN);
  float* Lm = alloc(NN);
  float* Pparams = alloc(16);
  int* cnt = (int*)alloc(4 * (size_t)NN);
  int* rowptr = (int*)alloc(4 * (size_t)(NN + 1));
  int* cursor = (int*)alloc(4 * (size_t)NN);
  int* spart = (int*)alloc(4 * SCAN_NB);
  int2* ec2 = (int2*)alloc(2 * (size_t)EE);
  int2* eu2 = (int2*)alloc(2 * (size_t)EE);
  int2* tc3 = (int2*)alloc(2 * (size_t)TT);
  int2* tuv = (int2*)alloc(4 * (size_t)TT);
  if (off * sizeof(float) > ws_size) return;

  int* cnt_c2 = cnt, *cnt_u2 = cnt + NN, *cnt_c3 = cnt + 2 * NN, *cnt_uv = cnt + 3 * NN;
  int* rp_c2 = rowptr, *rp_u2 = rowptr + (NN + 1), *rp_c3 = rowptr + 2 * (NN + 1), *rp_uv = rowptr + 3 * (NN + 1);
  int* cu_c2 = cursor, *cu_u2 = cursor + NN, *cu_c3 = cursor + 2 * NN, *cu_uv = cursor + 3 * NN;

  hipMemsetAsync(cnt, 0, 4ull * NN * sizeof(int), stream);
  hipMemsetAsync(out + ND, 0, sizeof(float), stream);

  params_k<<<1, 64, 0, stream>>>(l2s, l3s, lms, b2s, b3s, bms, Pparams);

  int rowB = (NN + 3) / 4;
  int mB = (NN + 63) / 64;

  ln_fwd<<<rowB, 256, 0, stream>>>(X, ln_g, ln_b, Gb, meanv, rstdv);
  w_conv<<<320, 256, 0, stream>>>(W_Q2, W_K2, W_Q3, W_K3, W_Qm, Wt5, Wcat);
  mfma_fwd<<<dim3(mB, 10), 256, 0, stream>>>((const ushort_t*)Gb, Wt5, (ushort_t*)QKall, NN);
  gemm_km<<<1, 256, 0, stream>>>(B_mem, W_Km, Km, KM);
  edge_mlp<<<EE / 256, 256, 0, stream>>>(EA, We1, be1, We2, be2, a2);

  hist2<<<(EE + 255) / 256, 256, 0, stream>>>(c2, u2, cnt_c2, cnt_u2, EE);
  hist_t3<<<(TT + 255) / 256, 256, 0, stream>>>(c3, u3, v3, cnt_c3, cnt_uv, TT);
  scan_p1<<<dim3(SCAN_NB, 4), 256, 0, stream>>>(cnt, spart);
  scan_p2<<<1, 256, 0, stream>>>(spart);
  scan_p3<<<dim3(SCAN_NB, 4), 256, 0, stream>>>(cnt, spart, rowptr, cursor);
  scat2<<<(EE + 255) / 256, 256, 0, stream>>>(c2, u2, a2, cu_c2, cu_u2, ec2, eu2, EE);
  scat_t3<<<(TT + 255) / 256, 256, 0, stream>>>(c3, u3, v3, ttau, cu_c3, cu_uv, tc3, tuv, TT);

  e2_fused<<<rowB, 256, 0, stream>>>(QKall, Pparams, ec2, rp_c2, s2c, L2, dAll);
  dk2_gather<<<rowB, 256, 0, stream>>>(QKall, s2c, L2, Pparams, eu2, rp_u2, dAll);
  t3_fused<<<rowB, 256, 0, stream>>>(QKall, T_tau, Pparams, tc3, rp_c3, s3c, L3, dAll);
  dk3_gather<<<rowB, 256, 0, stream>>>(QKall, T_tau, s3c, L3, Pparams, tuv, rp_uv, dAll);
  em_row<<<rowB, 256, 0, stream>>>(QKall, Km, Pparams, dAll, Lm);

  mfma_bwd<<<dim3(mB, 2), 256, 0, stream>>>((const ushort_t*)dAll, Wcat, dG, NN);

  ln_bwd<<<rowB, 256, 0, stream>>>(X, dG, ln_g, meanv, rstdv, out);
  eval_write<<<(NN + 255) / 256, 256, 0, stream>>>(L2, L3, Lm, Pparams, out + ND);
}